// Round 11
// baseline (428.506 us; speedup 1.0000x reference)
//
#include <hip/hip_runtime.h>
#include <hip/hip_bf16.h>
#include <math.h>

typedef __hip_bfloat16 bf16;
typedef __attribute__((ext_vector_type(8))) short short8;
typedef __attribute__((ext_vector_type(4))) short short4v;
typedef __attribute__((ext_vector_type(4))) unsigned short ushort4v;
typedef __attribute__((ext_vector_type(4))) float f32x4;
typedef unsigned int u32;

#define BB 8
#define CC 256
#define NTOKB 4096
#define FF 256
#define HIDDEN 1024
#define NTOK (BB*NTOKB)     // 32768

#if defined(__has_builtin)
#if __has_builtin(__builtin_amdgcn_global_load_lds)
#define HAS_GLL 1
#endif
#endif
#ifndef HAS_GLL
#define HAS_GLL 0
#endif

__device__ __forceinline__ float bf2f(bf16 x) { return __bfloat162float(x); }
__device__ __forceinline__ bf16 f2bf(float x) { return __float2bfloat16(x); }
__device__ __forceinline__ float clampf(float v, float lo, float hi) {
    return fminf(fmaxf(v, lo), hi);
}
__device__ __forceinline__ float s2f(short s) {
    unsigned int u = ((unsigned int)(unsigned short)s) << 16;
    float f; __builtin_memcpy(&f, &u, 4); return f;
}
__device__ __forceinline__ unsigned short f2bits(float v) {
    bf16 h = f2bf(v);
    unsigned short b; __builtin_memcpy(&b, &h, 2); return b;
}

// Abramowitz-Stegun 7.1.26 erf: |err| <= 1.5e-7 (below fp32/bf16 noise).
__device__ __forceinline__ float fast_erf(float x) {
    float ax = fabsf(x);
    float t = __builtin_amdgcn_rcpf(fmaf(0.3275911f, ax, 1.f));
    float p = fmaf(t, 1.061405429f, -1.453152027f);
    p = fmaf(t, p, 1.421413741f);
    p = fmaf(t, p, -0.284496736f);
    p = fmaf(t, p, 0.254829592f);
    p = p * t;
    float e = __expf(-ax * ax);
    float r = fmaf(-p, e, 1.f);
    return x < 0.f ? -r : r;
}

#if HAS_GLL
__device__ __forceinline__ void gll16(const void* g, void* l) {
    __builtin_amdgcn_global_load_lds(
        (const __attribute__((address_space(1))) u32*)g,
        (__attribute__((address_space(3))) u32*)l, 16, 0, 0);
}
#endif

__device__ __forceinline__ float ldin(const void* p, size_t i, int fp32mode) {
    float v = fp32mode ? ((const float*)p)[i] : __bfloat162float(((const bf16*)p)[i]);
    if (!(v == v)) v = 0.f;
    return clampf(v, -1e4f, 1e4f);
}

__device__ __forceinline__ float wave_sum(float v) {
#pragma unroll
    for (int off = 32; off > 0; off >>= 1) v += __shfl_xor(v, off, 64);
    return v;
}

__global__ void detect_mode(const void* __restrict__ x, int* __restrict__ flag) {
    int i = threadIdx.x;
    float vb = __bfloat162float(((const bf16*)x)[(size_t)i * 37 + 1]);
    int bad = (!(vb == vb)) || (fabsf(vb) > 1e4f);
    unsigned long long m = __ballot(bad);
    if (i == 0) *flag = (m != 0ull) ? 1 : 0;
}

// Pre-convert all weight matrices to bf16 once + pack QKV biases to fp32.
__global__ void convw_all(const void* __restrict__ wq, const void* __restrict__ wk,
                          const void* __restrict__ wa, const void* __restrict__ proj,
                          const void* __restrict__ w1, const void* __restrict__ w2,
                          const void* __restrict__ bq, const void* __restrict__ bk,
                          const void* __restrict__ ba,
                          bf16* __restrict__ dst, float* __restrict__ bqkv,
                          const int* __restrict__ mode) {
    int fp32 = *mode;
    int i = blockIdx.x * 256 + threadIdx.x;    // 0 .. 787199
    if (i < 786432) {
        const void* src; size_t off;
        if (i < 262144) {
            int seg = i >> 16; off = (size_t)(i & 65535);
            src = seg == 0 ? wq : seg == 1 ? wk : seg == 2 ? wa : proj;
        } else if (i < 524288) { src = w1; off = (size_t)(i - 262144); }
        else { src = w2; off = (size_t)(i - 524288); }
        dst[i] = f2bf(ldin(src, off, fp32));
    } else if (i < 787200) {
        int j = i - 786432;
        const void* s = j < 256 ? bq : j < 512 ? bk : ba;
        bqkv[j] = ldin(s, (size_t)(j & 255), fp32);
    }
}

// ============================================================================
//  trans_ln: fused input-transpose + LayerNorm1 (write phase: one wave per
//  token, lane l -> channels [4l,4l+4) = fully coalesced 512B wave stores).
// ============================================================================
__global__ __launch_bounds__(256) void trans_ln(const void* __restrict__ X,
        const void* __restrict__ g, const void* __restrict__ bta,
        bf16* __restrict__ T, bf16* __restrict__ H,
        const int* __restrict__ mode) {
    __shared__ float tile[CC][33];
    __shared__ float ps[8][32], ps2[8][32];
    __shared__ float mu_s[32], rs_s[32];
    int fp32 = *mode;
    int b = blockIdx.y;
    int n0 = blockIdx.x * 32;
    int tx = threadIdx.x & 31, ty = threadIdx.x >> 5;   // 256 threads = 32x8
    size_t eoff = (size_t)b * CC * NTOKB;
    for (int c0 = 0; c0 < CC; c0 += 32)
        for (int i = ty; i < 32; i += 8)
            tile[c0 + i][tx] = ldin(X, eoff + (size_t)(c0 + i) * NTOKB + n0 + tx, fp32);
    __syncthreads();
    {
        float s = 0.f, s2 = 0.f;
#pragma unroll 8
        for (int c = ty * 32; c < ty * 32 + 32; c++) {
            float v = tile[c][tx]; s += v; s2 += v * v;
        }
        ps[ty][tx] = s; ps2[ty][tx] = s2;
    }
    __syncthreads();
    if (threadIdx.x < 32) {
        float s = 0.f, s2 = 0.f;
#pragma unroll
        for (int p = 0; p < 8; p++) { s += ps[p][threadIdx.x]; s2 += ps2[p][threadIdx.x]; }
        float mu = s * (1.f / CC);
        float var = s2 * (1.f / CC) - mu * mu;
        mu_s[threadIdx.x] = mu;
        rs_s[threadIdx.x] = rsqrtf(fmaxf(var, 0.f) + 1e-5f);
    }
    __syncthreads();
    int wv = threadIdx.x >> 6;          // 0..3
    int lane = threadIdx.x & 63;
    int cbase = lane * 4;
    float gv[4], bvv[4];
#pragma unroll
    for (int q = 0; q < 4; q++) {
        gv[q] = ldin(g, cbase + q, fp32);
        bvv[q] = ldin(bta, cbase + q, fp32);
    }
    for (int tk = wv; tk < 32; tk += 4) {
        float mu = mu_s[tk], rstd = rs_s[tk];
        ushort4v tpack, hpack;
#pragma unroll
        for (int q = 0; q < 4; q++) {
            float v = tile[cbase + q][tk];
            tpack[q] = f2bits(v);
            hpack[q] = f2bits((v - mu) * rstd * gv[q] + bvv[q]);
        }
        size_t rowoff = ((size_t)b * NTOKB + n0 + tk) * CC + cbase;
        *(ushort4v*)((unsigned short*)T + rowoff) = tpack;
        *(ushort4v*)((unsigned short*)H + rowoff) = hpack;
    }
}

// ============================================================================
//                     SHARED SMALL KERNELS
// ============================================================================

__global__ void transpose_in_off(const void* __restrict__ X, bf16* __restrict__ T,
                                 const int* __restrict__ mode, size_t eoff) {
    __shared__ float tile[32][33];
    int fp32 = *mode;
    int n0 = blockIdx.x * 32, c0 = blockIdx.y * 32;
    int tx = threadIdx.x, ty = threadIdx.y;
    for (int i = ty; i < 32; i += 8)
        tile[i][tx] = ldin(X, eoff + (size_t)(c0 + i) * NTOKB + n0 + tx, fp32);
    __syncthreads();
    for (int i = ty; i < 32; i += 8)
        T[(size_t)(n0 + i) * CC + c0 + tx] = f2bf(tile[tx][i]);
}

__global__ void transpose_out_off(const bf16* __restrict__ T, void* __restrict__ O,
                                  const int* __restrict__ mode, size_t eoff) {
    __shared__ float tile[32][33];
    int fp32 = *mode;
    int c0 = blockIdx.x * 32, n0 = blockIdx.y * 32;
    int tx = threadIdx.x, ty = threadIdx.y;
    for (int i = ty; i < 32; i += 8)
        tile[i][tx] = bf2f(T[(size_t)(n0 + i) * CC + c0 + tx]);
    __syncthreads();
    for (int i = ty; i < 32; i += 8) {
        size_t idx = eoff + (size_t)(c0 + i) * NTOKB + n0 + tx;
        float v = tile[tx][i];
        if (fp32) ((float*)O)[idx] = v; else ((bf16*)O)[idx] = f2bf(v);
    }
}

__global__ void layernorm_k(const bf16* __restrict__ X, const void* __restrict__ g,
                            const void* __restrict__ bta, bf16* __restrict__ Y,
                            const int* __restrict__ mode) {
    int fp32 = *mode;
    int t = blockIdx.x * 4 + (threadIdx.x >> 6);
    int lane = threadIdx.x & 63;
    const bf16* row = X + (size_t)t * CC;
    float v[4], s = 0.f, s2 = 0.f;
#pragma unroll
    for (int j = 0; j < 4; j++) {
        v[j] = bf2f(row[lane + 64 * j]);
        s += v[j]; s2 += v[j] * v[j];
    }
    s = wave_sum(s); s2 = wave_sum(s2);
    float mu = s * (1.f / CC);
    float var = s2 * (1.f / CC) - mu * mu;
    float rstd = rsqrtf(fmaxf(var, 0.f) + 1e-5f);
    bf16* yrow = Y + (size_t)t * CC;
#pragma unroll
    for (int j = 0; j < 4; j++) {
        int c = lane + 64 * j;
        yrow[c] = f2bf((v[j] - mu) * rstd * ldin(g, c, fp32) + ldin(bta, c, fp32));
    }
}

__global__ void layernorm_v(const bf16* __restrict__ X, const void* __restrict__ g,
                            const void* __restrict__ bta, bf16* __restrict__ Y,
                            const int* __restrict__ mode) {
    int fp32 = *mode;
    int t = blockIdx.x * 4 + (threadIdx.x >> 6);
    int lane = threadIdx.x & 63;
    const short* row = (const short*)X + (size_t)t * CC;
    short4v u = *(const short4v*)&row[lane * 4];
    float v[4], s = 0.f, s2 = 0.f;
#pragma unroll
    for (int j = 0; j < 4; j++) { v[j] = s2f(u[j]); s += v[j]; s2 += v[j] * v[j]; }
    s = wave_sum(s); s2 = wave_sum(s2);
    float mu = s * (1.f / CC);
    float var = s2 * (1.f / CC) - mu * mu;
    float rstd = rsqrtf(fmaxf(var, 0.f) + 1e-5f);
    ushort4v o;
#pragma unroll
    for (int j = 0; j < 4; j++) {
        int c = lane * 4 + j;
        o[j] = f2bits((v[j] - mu) * rstd * ldin(g, c, fp32) + ldin(bta, c, fp32));
    }
    *(ushort4v*)((unsigned short*)Y + (size_t)t * CC + lane * 4) = o;
}

__global__ void rownorm_k(bf16* __restrict__ Q, float* __restrict__ DIAG) {
    int t = blockIdx.x * 4 + (threadIdx.x >> 6);
    int lane = threadIdx.x & 63;
    bf16* row = Q + (size_t)t * CC;
    float v[4], s2 = 0.f;
#pragma unroll
    for (int j = 0; j < 4; j++) { v[j] = bf2f(row[lane + 64 * j]); s2 += v[j] * v[j]; }
    s2 = wave_sum(s2);
    float nrm = sqrtf(fmaxf(s2, 0.f));
    float scale = 1.f / fmaxf(nrm, 5e-5f);
#pragma unroll
    for (int j = 0; j < 4; j++) row[lane + 64 * j] = f2bf(v[j] * scale);
    if (lane == 0) DIAG[t] = 0.5f * s2 * scale * scale;
}

// Read-only row-scale: SCALE = 1/max(||q||,5e-5), DIAG = 0.5*||q||^2*scale^2.
__global__ void rowscale_v(const bf16* __restrict__ Q, float* __restrict__ SCALE,
                           float* __restrict__ DIAG) {
    int t = blockIdx.x * 4 + (threadIdx.x >> 6);
    int lane = threadIdx.x & 63;
    const short* row = (const short*)Q + (size_t)t * CC;
    short4v u = *(const short4v*)&row[lane * 4];
    float s2 = 0.f;
#pragma unroll
    for (int j = 0; j < 4; j++) { float v = s2f(u[j]); s2 += v * v; }
    s2 = wave_sum(s2);
    if (lane == 0) {
        float nrm = sqrtf(fmaxf(s2, 0.f));
        float scale = 1.f / fmaxf(nrm, 5e-5f);
        SCALE[t] = scale;
        DIAG[t] = 0.5f * s2 * scale * scale;
    }
}

// ============================================================================
//                     FALLBACK (R5) GEMM KERNELS
// ============================================================================

template <int EPI>
__global__ void gemm_nt(const bf16* __restrict__ A, const void* __restrict__ Bw,
                        const void* __restrict__ bias, const float* __restrict__ diag,
                        const bf16* __restrict__ resid, bf16* __restrict__ Cm,
                        int M, int Nn, int Kk, const int* __restrict__ mode) {
    __shared__ float As[32][33];
    __shared__ float Bs[32][33];
    int fp32 = *mode;
    int tx = threadIdx.x, ty = threadIdx.y;
    int n0 = blockIdx.x * 32, m0 = blockIdx.y * 32;
    int tid = ty * 16 + tx;
    int lr = tid >> 5, lc = tid & 31;
    float acc[2][2] = {{0.f, 0.f}, {0.f, 0.f}};
    for (int k0 = 0; k0 < Kk; k0 += 32) {
#pragma unroll
        for (int i = 0; i < 4; i++) {
            int r = lr + 8 * i;
            As[r][lc] = bf2f(A[(size_t)(m0 + r) * Kk + k0 + lc]);
            Bs[r][lc] = ldin(Bw, (size_t)(n0 + r) * Kk + k0 + lc, fp32);
        }
        __syncthreads();
#pragma unroll
        for (int kk = 0; kk < 32; kk++) {
            float a0 = As[ty][kk], a1 = As[ty + 16][kk];
            float b0 = Bs[tx][kk], b1 = Bs[tx + 16][kk];
            acc[0][0] += a0 * b0; acc[0][1] += a0 * b1;
            acc[1][0] += a1 * b0; acc[1][1] += a1 * b1;
        }
        __syncthreads();
    }
#pragma unroll
    for (int i = 0; i < 2; i++)
#pragma unroll
        for (int j = 0; j < 2; j++) {
            int m = m0 + ty + 16 * i, n = n0 + tx + 16 * j;
            float v = acc[i][j];
            if (EPI == 0) {
                v = clampf(v + ldin(bias, n, fp32), -1e6f, 1e6f);
            } else if (EPI == 1) {
                v = fminf(0.0625f * (expf(fminf(v - diag[m], 60.f)) + 1e-4f), 1e8f);
            } else if (EPI == 2) {
                v += ldin(bias, n, fp32);
                v = 0.5f * v * (1.f + erff(v * 0.70710678118654752f));
            } else if (EPI == 3) {
                v += ldin(bias, n, fp32);
                v = clampf(v + bf2f(resid[(size_t)m * Nn + n]), -1e6f, 1e6f);
            }
            Cm[(size_t)m * Nn + n] = f2bf(v);
        }
}

__global__ void gemm_ctx_fb(const bf16* __restrict__ KP, const bf16* __restrict__ V,
                            float* __restrict__ CTX) {
    __shared__ float Ks[32][33];
    __shared__ float Vs[32][33];
    int c0 = blockIdx.x * 32, f0 = blockIdx.y * 32;
    int tx = threadIdx.x, ty = threadIdx.y;
    int tid = ty * 16 + tx, lr = tid >> 5, lc = tid & 31;
    float acc[2][2] = {{0.f, 0.f}, {0.f, 0.f}};
    for (int n0 = 0; n0 < NTOKB; n0 += 32) {
#pragma unroll
        for (int i = 0; i < 4; i++) {
            int r = lr + 8 * i;
            Ks[r][lc] = bf2f(KP[(size_t)(n0 + r) * FF + f0 + lc]);
            Vs[r][lc] = bf2f(V[(size_t)(n0 + r) * CC + c0 + lc]);
        }
        __syncthreads();
#pragma unroll
        for (int kk = 0; kk < 32; kk++) {
            float a0 = Ks[kk][ty], a1 = Ks[kk][ty + 16];
            float b0 = Vs[kk][tx], b1 = Vs[kk][tx + 16];
            acc[0][0] += a0 * b0; acc[0][1] += a0 * b1;
            acc[1][0] += a1 * b0; acc[1][1] += a1 * b1;
        }
        __syncthreads();
    }
#pragma unroll
    for (int i = 0; i < 2; i++)
#pragma unroll
        for (int j = 0; j < 2; j++)
            CTX[(size_t)(f0 + ty + 16 * i) * CC + c0 + tx + 16 * j] =
                clampf(acc[i][j], -1e18f, 1e18f);
}

__global__ void gemm_attnout_fb(const bf16* __restrict__ QP, const float* __restrict__ CTX,
                                const float* __restrict__ DINV, bf16* __restrict__ T) {
    __shared__ float As[32][33];
    __shared__ float Bs[32][33];
    int c0 = blockIdx.x * 32, m0 = blockIdx.y * 32;
    int tx = threadIdx.x, ty = threadIdx.y;
    int tid = ty * 16 + tx, lr = tid >> 5, lc = tid & 31;
    float acc[2][2] = {{0.f, 0.f}, {0.f, 0.f}};
    for (int k0 = 0; k0 < FF; k0 += 32) {
#pragma unroll
        for (int i = 0; i < 4; i++) {
            int r = lr + 8 * i;
            As[r][lc] = bf2f(QP[(size_t)(m0 + r) * FF + k0 + lc]);
            Bs[r][lc] = CTX[(size_t)(k0 + r) * CC + c0 + lc];
        }
        __syncthreads();
#pragma unroll
        for (int kk = 0; kk < 32; kk++) {
            float a0 = As[ty][kk], a1 = As[ty + 16][kk];
            float b0 = Bs[kk][tx], b1 = Bs[kk][tx + 16];
            acc[0][0] += a0 * b0; acc[0][1] += a0 * b1;
            acc[1][0] += a1 * b0; acc[1][1] += a1 * b1;
        }
        __syncthreads();
    }
#pragma unroll
    for (int i = 0; i < 2; i++)
#pragma unroll
        for (int j = 0; j < 2; j++) {
            int t = m0 + ty + 16 * i;
            size_t idx = (size_t)t * CC + c0 + tx + 16 * j;
            float addv = clampf(acc[i][j] * DINV[t], -1e6f, 1e6f);
            T[idx] = f2bf(bf2f(T[idx]) + addv);
        }
}

__global__ void colsum_k(const bf16* __restrict__ KP, float* __restrict__ KPART) {
    int chunk = blockIdx.x;
    int f = threadIdx.x;
    const bf16* base = KP + (size_t)chunk * 128 * FF + f;
    float acc = 0.f;
    for (int i = 0; i < 128; i++) acc += bf2f(base[(size_t)i * FF]);
    KPART[(size_t)chunk * FF + f] = acc;
}

__global__ void ksum_reduce(const float* __restrict__ KPART, float* __restrict__ KSUM) {
    int f = threadIdx.x;
    float acc = 0.f;
#pragma unroll
    for (int c = 0; c < 32; c++) acc += KPART[(size_t)c * FF + f];
    KSUM[f] = acc;
}

__global__ void dinv_k(const bf16* __restrict__ QP, const float* __restrict__ KSUM,
                       float* __restrict__ DINV) {
    int t = blockIdx.x * 4 + (threadIdx.x >> 6);
    int lane = threadIdx.x & 63;
    const bf16* row = QP + (size_t)t * FF;
    float s = 0.f;
#pragma unroll
    for (int j = 0; j < 4; j++) { int c = lane + 64 * j; s += bf2f(row[c]) * KSUM[c]; }
    s = wave_sum(s);
    if (lane == 0) DINV[t] = fminf(1.f / fmaxf(s, 1e-30f), 1e6f);
}

// ============================================================================
//   FAST PATH: MFMA bf16 GEMM — BMxBN tile, 4 waves in 2x2, global_load_lds,
//   2-phase double-buffered K-loop with BK-wide K-steps (BK=64 halves the
//   barrier-drain count at K=256 vs BK=32 — the short-K GEMMs are
//   latency/barrier-bound: MFMA issue is ~5% of dispatch time, FETCH is
//   L2-resident). Pointer-bump staging. EPI 6 = fused QKV, EPI 7 = fused proj
//   (+row-scale), EPI 8 = MLP2 + residual + transposed d_out store.
// ============================================================================
template <int BM, int BN, int BK, int EPI, bool TRANSC>
__global__ __launch_bounds__(256) void mgemm(
    const bf16* __restrict__ A, int lda, long long aZ,
    const void* __restrict__ Bv, int ldb, long long bZ,
    const void* __restrict__ bias, const float* __restrict__ diag,
    const float* __restrict__ dinv,
    bf16* __restrict__ Cb, int ldc,
    bf16* __restrict__ Cb2, bf16* __restrict__ Cb3, float* __restrict__ Cf,
    int MperZ, int Kc, int nchunk, const int* __restrict__ mode)
{
    constexpr int MI = BM / 32;          // per-wave 16-row tiles (wave covers BM/2)
    constexpr int NI = BN / 32;          // per-wave 16-col tiles (wave covers BN/2)
    constexpr int LPR = BK / 8;          // lanes per LDS row (16B per lane)
    constexpr int RPG = 64 / LPR;        // rows covered by one gll16 (wave)
    constexpr int NGA = (BM / 4) / RPG;  // gll16 per wave for A tile
    constexpr int NGB = (BN / 4) / RPG;  // gll16 per wave for B tile
    __shared__ short As[2][BM][BK];
    __shared__ short Bs[2][BN][BK];
    int fp32 = *mode;
    int z = blockIdx.z;
    int bl = z / nchunk;
    int chunk = z - bl * nchunk;
    const short* Ag = (const short*)A + (size_t)bl * aZ;
    const short* Bg = (const short*)Bv + (size_t)bl * bZ;

    // XCD swizzle: n-blocks of one m-panel get linear ids differing by 8 so
    // round-robin dispatch puts them on the SAME XCD (A-panel L2 reuse).
    int bx = blockIdx.x, by = blockIdx.y;
    if ((gridDim.y & 7) == 0) {
        int NB = gridDim.x;
        int flat = by * NB + bx;
        int grp = flat / (8 * NB);
        int rem = flat - grp * 8 * NB;
        by = grp * 8 + (rem & 7);
        bx = rem >> 3;
    }
    int n0 = bx * BN, m0 = by * BM;

    int tid = threadIdx.x;
    int lane = tid & 63, wave = tid >> 6;
    int wm = wave >> 1, wn = wave & 1;
    int row16 = lane & 15, quad = lane >> 4;
    int lrow = lane / LPR, lcol = (lane % LPR) * 8;

    f32x4 acc[MI][NI];
#pragma unroll
    for (int i = 0; i < MI; i++)
#pragma unroll
        for (int j = 0; j < NI; j++) acc[i][j] = {0.f, 0.f, 0.f, 0.f};

    const int arb = wave * (BM / 4);
    const int brb = wave * (BN / 4);

    int kBase = chunk * Kc;
    int nt = Kc / BK;

    // per-thread global source pointers, computed ONCE, bumped +BK per K-step
    const short* aptr[NGA];
    const short* bptr[NGB];
#pragma unroll
    for (int t = 0; t < NGA; t++)
        aptr[t] = &Ag[(size_t)(m0 + arb + t * RPG + lrow) * lda + kBase + lcol];
#pragma unroll
    for (int t = 0; t < NGB; t++)
        bptr[t] = &Bg[(size_t)(n0 + brb + t * RPG + lrow) * ldb + kBase + lcol];

    auto stage = [&](int b) {
#pragma unroll
        for (int t = 0; t < NGA; t++) {
#if HAS_GLL
            gll16(aptr[t], &As[b][arb + t * RPG][0]);
#else
            *(short8*)&As[b][arb + t * RPG + lrow][lcol] = *(const short8*)aptr[t];
#endif
            aptr[t] += BK;
        }
#pragma unroll
        for (int t = 0; t < NGB; t++) {
#if HAS_GLL
            gll16(bptr[t], &Bs[b][brb + t * RPG][0]);
#else
            *(short8*)&Bs[b][brb + t * RPG + lrow][lcol] = *(const short8*)bptr[t];
#endif
            bptr[t] += BK;
        }
    };

    auto compute = [&](int b) {
#pragma unroll
        for (int ko = 0; ko < BK; ko += 32) {
            short8 af[MI], bfr[NI];
#pragma unroll
            for (int i = 0; i < MI; i++)
                af[i] = *(const short8*)&As[b][wm * (BM / 2) + i * 16 + row16][quad * 8 + ko];
#pragma unroll
            for (int j = 0; j < NI; j++)
                bfr[j] = *(const short8*)&Bs[b][wn * (BN / 2) + j * 16 + row16][quad * 8 + ko];
#pragma unroll
            for (int i = 0; i < MI; i++)
#pragma unroll
                for (int j = 0; j < NI; j++)
                    acc[i][j] = __builtin_amdgcn_mfma_f32_16x16x32_bf16(af[i], bfr[j], acc[i][j], 0, 0, 0);
        }
    };

    // prologue: fill buffer 0 (__syncthreads drains vmcnt so LDS is ready)
    stage(0);
    __syncthreads();

    int cur = 0;
    for (int t = 0; t + 1 < nt; ++t) {
        stage(cur ^ 1);                        // next tile in flight under MFMAs
        compute(cur);
        __syncthreads();                       // drains vmcnt(0): next buf complete
        cur ^= 1;
    }
    compute(cur);                              // last tile, no prefetch

    // ---- epilogue ----
    float bv[NI];
    if (EPI == 0 || EPI == 2 || EPI == 3 || EPI == 8) {
#pragma unroll
        for (int j = 0; j < NI; j++)
            bv[j] = ldin(bias, n0 + wn * (BN / 2) + j * 16 + row16, fp32);
    } else if (EPI == 6) {
#pragma unroll
        for (int j = 0; j < NI; j++)
            bv[j] = diag[n0 + wn * (BN / 2) + j * 16 + row16];   // packed fp32 QKV bias
    } else {
#pragma unroll
        for (int j = 0; j < NI; j++) bv[j] = 0.f;
    }

#pragma unroll
    for (int i = 0; i < MI; i++) {
        int mb = m0 + wm * (BM / 2) + i * 16 + quad * 4;
        float dg[4] = {0.f, 0.f, 0.f, 0.f};
        if (EPI == 1) {
#pragma unroll
            for (int r = 0; r < 4; r++) dg[r] = diag[mb + r];
        }
        if (EPI == 7) {
#pragma unroll
            for (int r = 0; r < 4; r++) dg[r] = diag[(size_t)bl * MperZ + mb + r];
        }
        float dvv[4] = {0.f, 0.f, 0.f, 0.f};
        if (EPI == 5 || EPI == 7) {
#pragma unroll
            for (int r = 0; r < 4; r++) dvv[r] = dinv[(size_t)bl * MperZ + mb + r];
        }
#pragma unroll
        for (int j = 0; j < NI; j++) {
            int n = n0 + wn * (BN / 2) + j * 16 + row16;
            if (EPI == 6) {
                // fused QKV: seg is block-uniform (BN=128 divides 256-wide segments)
                int seg = n0 >> 8;          // 0=Q, 1=K, 2=V
                int c = n & 255;
                if (seg == 2) {
                    ushort4v pack;
#pragma unroll
                    for (int r = 0; r < 4; r++)
                        pack[r] = f2bits(clampf(acc[i][j][r] + bv[j], -1e6f, 1e6f));
                    int blq = mb >> 12, tb = mb & 4095;
                    *(ushort4v*)((unsigned short*)Cb3 +
                        (size_t)blq * CC * NTOKB + (size_t)c * NTOKB + tb) = pack;
                } else {
                    bf16* dst = seg ? Cb2 : Cb;
#pragma unroll
                    for (int r = 0; r < 4; r++) {
                        float v = clampf(acc[i][j][r] + bv[j], -1e6f, 1e6f);
                        dst[(size_t)(mb + r) * CC + c] = f2bf(v);
                    }
                }
            } else if (EPI == 7) {
                // fused proj with row-scale: dot*scale applied in fp32 (Q/K not
                // renormalized in memory). z=0 -> QP row-major; z=1 -> KP^T.
                if (bl == 1) {
                    ushort4v pack;
#pragma unroll
                    for (int r = 0; r < 4; r++) {
                        float v = fminf(0.0625f * (__expf(fminf(acc[i][j][r] * dvv[r] - dg[r], 60.f)) + 1e-4f), 1e8f);
                        pack[r] = f2bits(v);
                    }
                    int blq = mb >> 12, tb = mb & 4095;
                    *(ushort4v*)((unsigned short*)Cb2 +
                        (size_t)blq * CC * NTOKB + (size_t)n * NTOKB + tb) = pack;
                } else {
#pragma unroll
                    for (int r = 0; r < 4; r++) {
                        float v = fminf(0.0625f * (__expf(fminf(acc[i][j][r] * dvv[r] - dg[r], 60.f)) + 1e-4f), 1e8f);
                        Cb[(size_t)(mb + r) * ldc + n] = f2bf(v);
                    }
                }
            } else if (EPI == 8) {
                // MLP2: bias + residual(Cb=T) -> bf16-round -> transposed d_out
                int blq = mb >> 12, tb = mb & 4095;
                if (fp32) {
                    f32x4 o;
#pragma unroll
                    for (int r = 0; r < 4; r++) {
                        float v = acc[i][j][r] + bv[j];
                        v = clampf(v + bf2f(Cb[(size_t)(mb + r) * ldc + n]), -1e6f, 1e6f);
                        o[r] = bf2f(f2bf(v));
                    }
                    *(f32x4*)((float*)Cb3 + ((size_t)blq * CC + n) * NTOKB + tb) = o;
                } else {
                    ushort4v pack;
#pragma unroll
                    for (int r = 0; r < 4; r++) {
                        float v = acc[i][j][r] + bv[j];
                        v = clampf(v + bf2f(Cb[(size_t)(mb + r) * ldc + n]), -1e6f, 1e6f);
                        pack[r] = f2bits(v);
                    }
                    *(ushort4v*)((unsigned short*)Cb3 + ((size_t)blq * CC + n) * NTOKB + tb) = pack;
                }
            } else if (TRANSC) {
                ushort4v pack;
#pragma unroll
                for (int r = 0; r < 4; r++) {
                    float v = acc[i][j][r];
                    if (EPI == 0) {
                        v = clampf(v + bv[j], -1e6f, 1e6f);
                    } else {   // EPI == 1
                        v = fminf(0.0625f * (__expf(fminf(v - dg[r], 60.f)) + 1e-4f), 1e8f);
                    }
                    pack[r] = f2bits(v);
                }
                int blq = mb >> 12, tb = mb & 4095;
                *(ushort4v*)((unsigned short*)Cb +
                    (size_t)blq * CC * NTOKB + (size_t)n * NTOKB + tb) = pack;
            } else {
#pragma unroll
                for (int r = 0; r < 4; r++) {
                    int m = mb + r;
                    float v = acc[i][j][r];
                    if (EPI == 0) {
                        v = clampf(v + bv[j], -1e6f, 1e6f);
                        Cb[(size_t)m * ldc + n] = f2bf(v);
                    } else if (EPI == 1) {
                        v = fminf(0.0625f * (__expf(fminf(v - dg[r], 60.f)) + 1e-4f), 1e8f);
                        Cb[(size_t)m * ldc + n] = f2bf(v);
                    } else if (EPI == 2) {
                        v += bv[j];
                        v = 0.5f * v * (1.f + fast_erf(v * 0.70710678118654752f));
                        Cb[(size_t)m * ldc + n] = f2bf(v);
                    } else if (EPI == 3) {
                        v += bv[j];
                        size_t idx = (size_t)m * ldc + n;
                        v = clampf(v + bf2f(Cb[idx]), -1e6f, 1e6f);
                        Cb[idx] = f2bf(v);
                    } else if (EPI == 4) {
                        Cf[(size_t)z * MperZ + (size_t)m * ldc + n] = v;
                    } else if (EPI == 5) {
                        size_t mg = (size_t)bl * MperZ + m;
                        float addv = clampf(v * dvv[r], -1e6f, 1e6f);
                        size_t idx = mg * ldc + n;
                        Cb[idx] = f2bf(bf2f(Cb[idx]) + addv);
                    }
                }
            }
        }
    }
}

// PART[z=bl*16+ch][f][c] (fp32) -> CTX_T[bl][c][f] (bf16)
__global__ void reduce_ctx(const float* __restrict__ PART, bf16* __restrict__ CTXT) {
    int f = blockIdx.x;
    int bl = blockIdx.y;
    int c = threadIdx.x;
    float s = 0.f;
#pragma unroll
    for (int ch = 0; ch < 16; ch++)
        s += PART[(((size_t)bl * 16 + ch) * FF + f) * CC + c];
    s = clampf(s, -1e18f, 1e18f);
    CTXT[((size_t)bl * CC + c) * FF + f] = f2bf(s);
}

__global__ void colsum_t(const bf16* __restrict__ KPT, float* __restrict__ KSUM) {
    int bl = blockIdx.y;
    int f = blockIdx.x * 4 + (threadIdx.x >> 6);
    int lane = threadIdx.x & 63;
    const short* row = (const short*)KPT + ((size_t)bl * FF + f) * NTOKB;
    float s = 0.f;
    for (int i = lane * 8; i < NTOKB; i += 512) {
        short8 v = *(const short8*)&row[i];
#pragma unroll
        for (int j = 0; j < 8; j++) s += s2f(v[j]);
    }
    s = wave_sum(s);
    if (lane == 0) KSUM[(size_t)bl * FF + f] = s;
}

__global__ void dinv_v(const bf16* __restrict__ QP, const float* __restrict__ KSUM,
                       float* __restrict__ DINV) {
    int bl = blockIdx.y;
    int t = blockIdx.x * 4 + (threadIdx.x >> 6);
    int lane = threadIdx.x & 63;
    const short* row = (const short*)QP + ((size_t)bl * NTOKB + t) * FF;
    const float* ks = KSUM + (size_t)bl * FF;
    short4v u = *(const short4v*)&row[lane * 4];
    float s = 0.f;
#pragma unroll
    for (int j = 0; j < 4; j++) s += s2f(u[j]) * ks[lane * 4 + j];
    s = wave_sum(s);
    if (lane == 0) DINV[(size_t)bl * NTOKB + t] = fminf(1.f / fmaxf(s, 1e-30f), 1e6f);
}

// ============================================================================
extern "C" void kernel_launch(void* const* d_in, const int* in_sizes, int n_in,
                              void* d_out, int out_size, void* d_ws, size_t ws_size,
                              hipStream_t stream) {
    const void* x    = d_in[0];
    const void* proj = d_in[1];
    const void* wq   = d_in[2];
    const void* bq   = d_in[3];
    const void* wk   = d_in[4];
    const void* bk   = d_in[5];
    const void* wa   = d_in[6];
    const void* ba   = d_in[7];
    const void* g1   = d_in[8];
    const void* b1   = d_in[9];
    const void* g2   = d_in[10];
    const void* b2   = d_in[11];
    const void* w1   = d_in[12];
    const void* fb1  = d_in[13];
    const void* w2   = d_in[14];
    const void* fb2  = d_in[15];

    char* base = (char*)d_ws;
    const size_t MB = 1048576ull;
    const bool fast = ws_size >= 168 * MB;   // ws confirmed 256 MiB

    if (fast) {
        // ---- full-batch layout (peak ~167 MiB) ----
        bf16* T    = (bf16*)base;                    // [0,16M)
        bf16* Hs   = (bf16*)(base + 16 * MB);        // [16,32M)  H -> QP -> H2
        bf16* Qs   = (bf16*)(base + 32 * MB);        // [32,48M)  Q
        bf16* Ks   = (bf16*)(base + 48 * MB);        // [48,64M)  K
        bf16* VT   = (bf16*)(base + 64 * MB);        // [64,80M)  V_T
        bf16* KPT  = (bf16*)(base + 80 * MB);        // [80,96M)  KP_T
        bf16* MID  = (bf16*)(base + 96 * MB);        // [96,160M) MLP hidden
        float* PART = (float*)(base + 96 * MB);      // 34M fp32; dead before MID written
        char* sm = base + 160 * MB;
        int* MODE = (int*)sm;
        float* DIAGQ = (float*)(sm + 1024);          // NTOK  (DIAGK contiguous after)
        float* DIAGK = DIAGQ + NTOK;
        float* DINV  = DIAGK + NTOK;
        float* KSUM  = DINV + NTOK;                  // BB*FF
        float* SCALEQ = KSUM + BB * FF;              // NTOK  (SCALEK contiguous after)
        float* SCALEK = SCALEQ + NTOK;
        bf16* CTXT   = (bf16*)(sm + 2 * MB);         // 1M
        bf16* WB     = (bf16*)(sm + 4 * MB);         // 1.5M
        float* BQKV  = (float*)(sm + 6 * MB);        // 3KB

        detect_mode<<<1, 64, 0, stream>>>(x, MODE);
        convw_all<<<3075, 256, 0, stream>>>(wq, wk, wa, proj, w1, w2,
                                            bq, bk, ba, WB, BQKV, MODE);
        // fused transpose + LN1: writes T (residual) and Hs (LN out)
        trans_ln<<<dim3(NTOKB / 32, BB), 256, 0, stream>>>(x, g1, b1, T, Hs, MODE);

        // fused QKV: M=32768 N=768 K=256; grid (6, 256) = 1536 blocks
        mgemm<128, 128, 64, 6, false><<<dim3(6, 256, 1), 256, 0, stream>>>(
            Hs, 256, 0, WB, 256, 0, nullptr, BQKV, nullptr,
            Qs, 256, Ks, VT, nullptr, 0, 256, 1, MODE);
        // read-only row scale (Q/K not rewritten)
        rowscale_v<<<NTOK / 4, 256, 0, stream>>>(Qs, SCALEQ, DIAGQ);
        rowscale_v<<<NTOK / 4, 256, 0, stream>>>(Ks, SCALEK, DIAGK);
        // fused proj: z=0 Q->QP(Hs), z=1 K->KP^T(KPT); scale applied in epilogue
        mgemm<128, 128, 64, 7, false><<<dim3(2, 256, 2), 256, 0, stream>>>(
            Qs, 256, 8388608LL /*Ks-Qs elems*/, WB + 196608, 256, 0,
            nullptr, DIAGQ, SCALEQ,
            Hs, 256, KPT, nullptr, nullptr, NTOK, 256, 1, MODE);
        bf16* QP = Hs;
        colsum_t<<<dim3(FF / 4, BB), 256, 0, stream>>>(KPT, KSUM);
        dinv_v<<<dim3(NTOKB / 4, BB), 256, 0, stream>>>(QP, KSUM, DINV);
        // ctx: M=F=256, N=C=256, K=4096 split 16; z = 8 batches * 16 chunks = 128
        mgemm<64, 128, 64, 4, false><<<dim3(2, 4, BB * 16), 256, 0, stream>>>(
            KPT, NTOKB, (long long)FF * NTOKB, VT, NTOKB, (long long)CC * NTOKB,
            nullptr, nullptr, nullptr,
            nullptr, CC, nullptr, nullptr, PART, FF * CC, 256, 16, MODE);
        reduce_ctx<<<dim3(FF, BB), 256, 0, stream>>>(PART, CTXT);
        // attnout: M=4096/batch, N=256, K=256; BN=64 -> (4, 32, 8) = 1024 blocks
        mgemm<128, 64, 64, 5, false><<<dim3(4, 32, BB), 256, 0, stream>>>(
            QP, 256, (long long)NTOKB * FF, CTXT, FF, (long long)CC * FF,
            nullptr, nullptr, DINV,
            T, 256, nullptr, nullptr, nullptr, NTOKB, 256, 1, MODE);
        // MLP
        layernorm_v<<<NTOK / 4, 256, 0, stream>>>(T, g2, b2, Hs, MODE);
        mgemm<128, 128, 64, 2, false><<<dim3(8, 256, 1), 256, 0, stream>>>(
            Hs, 256, 0, WB + 262144, 256, 0, fb1, nullptr, nullptr,
            MID, 1024, nullptr, nullptr, nullptr, 0, 256, 1, MODE);
        // MLP2 fused with residual + transposed output store (EPI 8)
        mgemm<128, 128, 64, 8, false><<<dim3(2, 256, 1), 256, 0, stream>>>(
            MID, 1024, 0, WB + 524288, 1024, 0, fb2, nullptr, nullptr,
            T, 256, nullptr, (bf16*)d_out, nullptr, 0, 1024, 1, MODE);
        return;
    }

    // ================= FALLBACK: proven R5 per-batch path =================
    bf16* Tb   = (bf16*)(base);
    bf16* Hb   = (bf16*)(base + 2 * MB);
    bf16* Qb   = (bf16*)(base + 4 * MB);
    bf16* Kb   = (bf16*)(base + 6 * MB);
    bf16* Vb   = (bf16*)(base + 8 * MB);
    bf16* QPb  = (bf16*)(base + 2 * MB);
    bf16* KPb  = (bf16*)(base + 4 * MB);
    bf16* MIDb = (bf16*)(base + 2 * MB);
    bf16* H2b  = (bf16*)(base + 10 * MB);
    char* sm   = base + 12 * MB;
    int*   MODE  = (int*)sm;
    float* DIAGQ = (float*)(sm + 256);
    float* DIAGK = DIAGQ + NTOKB;
    float* DINV  = DIAGK + NTOKB;
    float* KSUM  = DINV + NTOKB;
    float* KPART = KSUM + FF;
    float* CTX   = KPART + 32 * FF;

    dim3 tb32(32, 8);
    dim3 tb16(16, 16);
    dim3 gq(CC / 32, NTOKB / 32);

    detect_mode<<<1, 64, 0, stream>>>(x, MODE);

    for (int b = 0; b < BB; b++) {
        size_t eoff = (size_t)b * CC * NTOKB;
        transpose_in_off<<<dim3(NTOKB / 32, CC / 32), tb32, 0, stream>>>(x, Tb, MODE, eoff);
        layernorm_k<<<NTOKB / 4, 256, 0, stream>>>(Tb, g1, b1, Hb, MODE);
        gemm_nt<0><<<gq, tb16, 0, stream>>>(Hb, wq, bq, nullptr, nullptr, Qb, NTOKB, CC, CC, MODE);
        gemm_nt<0><<<gq, tb16, 0, stream>>>(Hb, wk, bk, nullptr, nullptr, Kb, NTOKB, CC, CC, MODE);
        gemm_nt<0><<<gq, tb16, 0, stream>>>(Hb, wa, ba, nullptr, nullptr, Vb, NTOKB, CC, CC, MODE);
        rownorm_k<<<NTOKB / 4, 256, 0, stream>>>(Qb, DIAGQ);
        rownorm_k<<<NTOKB / 4, 256, 0, stream>>>(Kb, DIAGK);
        gemm_nt<1><<<gq, tb16, 0, stream>>>(Qb, proj, nullptr, DIAGQ, nullptr, QPb, NTOKB, FF, CC, MODE);
        gemm_nt<1><<<gq, tb16, 0, stream>>>(Kb, proj, nullptr, DIAGK, nullptr, KPb, NTOKB, FF, CC, MODE);
        colsum_k<<<32, 256, 0, stream>>>(KPb, KPART);
        ksum_reduce<<<1, 256, 0, stream>>>(KPART, KSUM);
        dinv_k<<<NTOKB / 4, 256, 0, stream>>>(QPb, KSUM, DINV);
        gemm_ctx_fb<<<dim3(CC / 32, FF / 32), tb16, 0, stream>>>(KPb, Vb, CTX);
        gemm_attnout_fb<<<gq, tb16, 0, stream>>>(QPb, CTX, DINV, Tb);
        layernorm_k<<<NTOKB / 4, 256, 0, stream>>>(Tb, g2, b2, H2b, MODE);
        gemm_nt<2><<<dim3(HIDDEN / 32, NTOKB / 32), tb16, 0, stream>>>(H2b, w1, fb1, nullptr, nullptr, MIDb, NTOKB, HIDDEN, CC, MODE);
        gemm_nt<3><<<gq, tb16, 0, stream>>>(MIDb, w2, fb2, nullptr, Tb, Tb, NTOKB, CC, HIDDEN, MODE);
        transpose_out_off<<<dim3(CC / 32, NTOKB / 32), tb32, 0, stream>>>(Tb, d_out, MODE, eoff);
    }
}

// Round 12
// 363.677 us; speedup vs baseline: 1.1783x; 1.1783x over previous
//
#include <hip/hip_runtime.h>
#include <hip/hip_bf16.h>
#include <math.h>

typedef __hip_bfloat16 bf16;
typedef __attribute__((ext_vector_type(8))) short short8;
typedef __attribute__((ext_vector_type(4))) short short4v;
typedef __attribute__((ext_vector_type(4))) unsigned short ushort4v;
typedef __attribute__((ext_vector_type(4))) float f32x4;
typedef unsigned int u32;

#define BB 8
#define CC 256
#define NTOKB 4096
#define FF 256
#define HIDDEN 1024
#define NTOK (BB*NTOKB)     // 32768

#if defined(__has_builtin)
#if __has_builtin(__builtin_amdgcn_global_load_lds)
#define HAS_GLL 1
#endif
#endif
#ifndef HAS_GLL
#define HAS_GLL 0
#endif

__device__ __forceinline__ float bf2f(bf16 x) { return __bfloat162float(x); }
__device__ __forceinline__ bf16 f2bf(float x) { return __float2bfloat16(x); }
__device__ __forceinline__ float clampf(float v, float lo, float hi) {
    return fminf(fmaxf(v, lo), hi);
}
__device__ __forceinline__ float s2f(short s) {
    unsigned int u = ((unsigned int)(unsigned short)s) << 16;
    float f; __builtin_memcpy(&f, &u, 4); return f;
}
__device__ __forceinline__ unsigned short f2bits(float v) {
    bf16 h = f2bf(v);
    unsigned short b; __builtin_memcpy(&b, &h, 2); return b;
}

// Abramowitz-Stegun 7.1.26 erf: |err| <= 1.5e-7 (below fp32/bf16 noise).
__device__ __forceinline__ float fast_erf(float x) {
    float ax = fabsf(x);
    float t = __builtin_amdgcn_rcpf(fmaf(0.3275911f, ax, 1.f));
    float p = fmaf(t, 1.061405429f, -1.453152027f);
    p = fmaf(t, p, 1.421413741f);
    p = fmaf(t, p, -0.284496736f);
    p = fmaf(t, p, 0.254829592f);
    p = p * t;
    float e = __expf(-ax * ax);
    float r = fmaf(-p, e, 1.f);
    return x < 0.f ? -r : r;
}

#if HAS_GLL
__device__ __forceinline__ void gll16(const void* g, void* l) {
    __builtin_amdgcn_global_load_lds(
        (const __attribute__((address_space(1))) u32*)g,
        (__attribute__((address_space(3))) u32*)l, 16, 0, 0);
}
#endif

__device__ __forceinline__ float ldin(const void* p, size_t i, int fp32mode) {
    float v = fp32mode ? ((const float*)p)[i] : __bfloat162float(((const bf16*)p)[i]);
    if (!(v == v)) v = 0.f;
    return clampf(v, -1e4f, 1e4f);
}

__device__ __forceinline__ float wave_sum(float v) {
#pragma unroll
    for (int off = 32; off > 0; off >>= 1) v += __shfl_xor(v, off, 64);
    return v;
}

__global__ void detect_mode(const void* __restrict__ x, int* __restrict__ flag) {
    int i = threadIdx.x;
    float vb = __bfloat162float(((const bf16*)x)[(size_t)i * 37 + 1]);
    int bad = (!(vb == vb)) || (fabsf(vb) > 1e4f);
    unsigned long long m = __ballot(bad);
    if (i == 0) *flag = (m != 0ull) ? 1 : 0;
}

// Pre-convert all weight matrices to bf16 once + pack QKV biases to fp32.
__global__ void convw_all(const void* __restrict__ wq, const void* __restrict__ wk,
                          const void* __restrict__ wa, const void* __restrict__ proj,
                          const void* __restrict__ w1, const void* __restrict__ w2,
                          const void* __restrict__ bq, const void* __restrict__ bk,
                          const void* __restrict__ ba,
                          bf16* __restrict__ dst, float* __restrict__ bqkv,
                          const int* __restrict__ mode) {
    int fp32 = *mode;
    int i = blockIdx.x * 256 + threadIdx.x;    // 0 .. 787199
    if (i < 786432) {
        const void* src; size_t off;
        if (i < 262144) {
            int seg = i >> 16; off = (size_t)(i & 65535);
            src = seg == 0 ? wq : seg == 1 ? wk : seg == 2 ? wa : proj;
        } else if (i < 524288) { src = w1; off = (size_t)(i - 262144); }
        else { src = w2; off = (size_t)(i - 524288); }
        dst[i] = f2bf(ldin(src, off, fp32));
    } else if (i < 787200) {
        int j = i - 786432;
        const void* s = j < 256 ? bq : j < 512 ? bk : ba;
        bqkv[j] = ldin(s, (size_t)(j & 255), fp32);
    }
}

// ============================================================================
//  trans_ln: fused input-transpose + LayerNorm1 (write phase: one wave per
//  token, lane l -> channels [4l,4l+4) = fully coalesced 512B wave stores).
// ============================================================================
__global__ __launch_bounds__(256) void trans_ln(const void* __restrict__ X,
        const void* __restrict__ g, const void* __restrict__ bta,
        bf16* __restrict__ T, bf16* __restrict__ H,
        const int* __restrict__ mode) {
    __shared__ float tile[CC][33];
    __shared__ float ps[8][32], ps2[8][32];
    __shared__ float mu_s[32], rs_s[32];
    int fp32 = *mode;
    int b = blockIdx.y;
    int n0 = blockIdx.x * 32;
    int tx = threadIdx.x & 31, ty = threadIdx.x >> 5;   // 256 threads = 32x8
    size_t eoff = (size_t)b * CC * NTOKB;
    for (int c0 = 0; c0 < CC; c0 += 32)
        for (int i = ty; i < 32; i += 8)
            tile[c0 + i][tx] = ldin(X, eoff + (size_t)(c0 + i) * NTOKB + n0 + tx, fp32);
    __syncthreads();
    {
        float s = 0.f, s2 = 0.f;
#pragma unroll 8
        for (int c = ty * 32; c < ty * 32 + 32; c++) {
            float v = tile[c][tx]; s += v; s2 += v * v;
        }
        ps[ty][tx] = s; ps2[ty][tx] = s2;
    }
    __syncthreads();
    if (threadIdx.x < 32) {
        float s = 0.f, s2 = 0.f;
#pragma unroll
        for (int p = 0; p < 8; p++) { s += ps[p][threadIdx.x]; s2 += ps2[p][threadIdx.x]; }
        float mu = s * (1.f / CC);
        float var = s2 * (1.f / CC) - mu * mu;
        mu_s[threadIdx.x] = mu;
        rs_s[threadIdx.x] = rsqrtf(fmaxf(var, 0.f) + 1e-5f);
    }
    __syncthreads();
    int wv = threadIdx.x >> 6;          // 0..3
    int lane = threadIdx.x & 63;
    int cbase = lane * 4;
    float gv[4], bvv[4];
#pragma unroll
    for (int q = 0; q < 4; q++) {
        gv[q] = ldin(g, cbase + q, fp32);
        bvv[q] = ldin(bta, cbase + q, fp32);
    }
    for (int tk = wv; tk < 32; tk += 4) {
        float mu = mu_s[tk], rstd = rs_s[tk];
        ushort4v tpack, hpack;
#pragma unroll
        for (int q = 0; q < 4; q++) {
            float v = tile[cbase + q][tk];
            tpack[q] = f2bits(v);
            hpack[q] = f2bits((v - mu) * rstd * gv[q] + bvv[q]);
        }
        size_t rowoff = ((size_t)b * NTOKB + n0 + tk) * CC + cbase;
        *(ushort4v*)((unsigned short*)T + rowoff) = tpack;
        *(ushort4v*)((unsigned short*)H + rowoff) = hpack;
    }
}

// ============================================================================
//                     SHARED SMALL KERNELS
// ============================================================================

__global__ void transpose_in_off(const void* __restrict__ X, bf16* __restrict__ T,
                                 const int* __restrict__ mode, size_t eoff) {
    __shared__ float tile[32][33];
    int fp32 = *mode;
    int n0 = blockIdx.x * 32, c0 = blockIdx.y * 32;
    int tx = threadIdx.x, ty = threadIdx.y;
    for (int i = ty; i < 32; i += 8)
        tile[i][tx] = ldin(X, eoff + (size_t)(c0 + i) * NTOKB + n0 + tx, fp32);
    __syncthreads();
    for (int i = ty; i < 32; i += 8)
        T[(size_t)(n0 + i) * CC + c0 + tx] = f2bf(tile[tx][i]);
}

__global__ void transpose_out_off(const bf16* __restrict__ T, void* __restrict__ O,
                                  const int* __restrict__ mode, size_t eoff) {
    __shared__ float tile[32][33];
    int fp32 = *mode;
    int c0 = blockIdx.x * 32, n0 = blockIdx.y * 32;
    int tx = threadIdx.x, ty = threadIdx.y;
    for (int i = ty; i < 32; i += 8)
        tile[i][tx] = bf2f(T[(size_t)(n0 + i) * CC + c0 + tx]);
    __syncthreads();
    for (int i = ty; i < 32; i += 8) {
        size_t idx = eoff + (size_t)(c0 + i) * NTOKB + n0 + tx;
        float v = tile[tx][i];
        if (fp32) ((float*)O)[idx] = v; else ((bf16*)O)[idx] = f2bf(v);
    }
}

__global__ void layernorm_k(const bf16* __restrict__ X, const void* __restrict__ g,
                            const void* __restrict__ bta, bf16* __restrict__ Y,
                            const int* __restrict__ mode) {
    int fp32 = *mode;
    int t = blockIdx.x * 4 + (threadIdx.x >> 6);
    int lane = threadIdx.x & 63;
    const bf16* row = X + (size_t)t * CC;
    float v[4], s = 0.f, s2 = 0.f;
#pragma unroll
    for (int j = 0; j < 4; j++) {
        v[j] = bf2f(row[lane + 64 * j]);
        s += v[j]; s2 += v[j] * v[j];
    }
    s = wave_sum(s); s2 = wave_sum(s2);
    float mu = s * (1.f / CC);
    float var = s2 * (1.f / CC) - mu * mu;
    float rstd = rsqrtf(fmaxf(var, 0.f) + 1e-5f);
    bf16* yrow = Y + (size_t)t * CC;
#pragma unroll
    for (int j = 0; j < 4; j++) {
        int c = lane + 64 * j;
        yrow[c] = f2bf((v[j] - mu) * rstd * ldin(g, c, fp32) + ldin(bta, c, fp32));
    }
}

__global__ void layernorm_v(const bf16* __restrict__ X, const void* __restrict__ g,
                            const void* __restrict__ bta, bf16* __restrict__ Y,
                            const int* __restrict__ mode) {
    int fp32 = *mode;
    int t = blockIdx.x * 4 + (threadIdx.x >> 6);
    int lane = threadIdx.x & 63;
    const short* row = (const short*)X + (size_t)t * CC;
    short4v u = *(const short4v*)&row[lane * 4];
    float v[4], s = 0.f, s2 = 0.f;
#pragma unroll
    for (int j = 0; j < 4; j++) { v[j] = s2f(u[j]); s += v[j]; s2 += v[j] * v[j]; }
    s = wave_sum(s); s2 = wave_sum(s2);
    float mu = s * (1.f / CC);
    float var = s2 * (1.f / CC) - mu * mu;
    float rstd = rsqrtf(fmaxf(var, 0.f) + 1e-5f);
    ushort4v o;
#pragma unroll
    for (int j = 0; j < 4; j++) {
        int c = lane * 4 + j;
        o[j] = f2bits((v[j] - mu) * rstd * ldin(g, c, fp32) + ldin(bta, c, fp32));
    }
    *(ushort4v*)((unsigned short*)Y + (size_t)t * CC + lane * 4) = o;
}

__global__ void rownorm_k(bf16* __restrict__ Q, float* __restrict__ DIAG) {
    int t = blockIdx.x * 4 + (threadIdx.x >> 6);
    int lane = threadIdx.x & 63;
    bf16* row = Q + (size_t)t * CC;
    float v[4], s2 = 0.f;
#pragma unroll
    for (int j = 0; j < 4; j++) { v[j] = bf2f(row[lane + 64 * j]); s2 += v[j] * v[j]; }
    s2 = wave_sum(s2);
    float nrm = sqrtf(fmaxf(s2, 0.f));
    float scale = 1.f / fmaxf(nrm, 5e-5f);
#pragma unroll
    for (int j = 0; j < 4; j++) row[lane + 64 * j] = f2bf(v[j] * scale);
    if (lane == 0) DIAG[t] = 0.5f * s2 * scale * scale;
}

// Read-only row-scale for BOTH Q and K in one launch (blockIdx.y = 0:Q, 1:K).
// Q/K buffers are contiguous (+8M elems); SCALE and DIAG arrays contiguous.
__global__ void rowscale2(const bf16* __restrict__ Q, float* __restrict__ SCALE,
                          float* __restrict__ DIAG) {
    int which = blockIdx.y;
    int t = blockIdx.x * 4 + (threadIdx.x >> 6);
    int lane = threadIdx.x & 63;
    const short* row = (const short*)Q + (size_t)which * NTOK * CC + (size_t)t * CC;
    short4v u = *(const short4v*)&row[lane * 4];
    float s2 = 0.f;
#pragma unroll
    for (int j = 0; j < 4; j++) { float v = s2f(u[j]); s2 += v * v; }
    s2 = wave_sum(s2);
    if (lane == 0) {
        float nrm = sqrtf(fmaxf(s2, 0.f));
        float scale = 1.f / fmaxf(nrm, 5e-5f);
        size_t idx = (size_t)which * NTOK + t;
        SCALE[idx] = scale;
        DIAG[idx] = 0.5f * s2 * scale * scale;
    }
}

// ============================================================================
//                     FALLBACK (R5) GEMM KERNELS
// ============================================================================

template <int EPI>
__global__ void gemm_nt(const bf16* __restrict__ A, const void* __restrict__ Bw,
                        const void* __restrict__ bias, const float* __restrict__ diag,
                        const bf16* __restrict__ resid, bf16* __restrict__ Cm,
                        int M, int Nn, int Kk, const int* __restrict__ mode) {
    __shared__ float As[32][33];
    __shared__ float Bs[32][33];
    int fp32 = *mode;
    int tx = threadIdx.x, ty = threadIdx.y;
    int n0 = blockIdx.x * 32, m0 = blockIdx.y * 32;
    int tid = ty * 16 + tx;
    int lr = tid >> 5, lc = tid & 31;
    float acc[2][2] = {{0.f, 0.f}, {0.f, 0.f}};
    for (int k0 = 0; k0 < Kk; k0 += 32) {
#pragma unroll
        for (int i = 0; i < 4; i++) {
            int r = lr + 8 * i;
            As[r][lc] = bf2f(A[(size_t)(m0 + r) * Kk + k0 + lc]);
            Bs[r][lc] = ldin(Bw, (size_t)(n0 + r) * Kk + k0 + lc, fp32);
        }
        __syncthreads();
#pragma unroll
        for (int kk = 0; kk < 32; kk++) {
            float a0 = As[ty][kk], a1 = As[ty + 16][kk];
            float b0 = Bs[tx][kk], b1 = Bs[tx + 16][kk];
            acc[0][0] += a0 * b0; acc[0][1] += a0 * b1;
            acc[1][0] += a1 * b0; acc[1][1] += a1 * b1;
        }
        __syncthreads();
    }
#pragma unroll
    for (int i = 0; i < 2; i++)
#pragma unroll
        for (int j = 0; j < 2; j++) {
            int m = m0 + ty + 16 * i, n = n0 + tx + 16 * j;
            float v = acc[i][j];
            if (EPI == 0) {
                v = clampf(v + ldin(bias, n, fp32), -1e6f, 1e6f);
            } else if (EPI == 1) {
                v = fminf(0.0625f * (expf(fminf(v - diag[m], 60.f)) + 1e-4f), 1e8f);
            } else if (EPI == 2) {
                v += ldin(bias, n, fp32);
                v = 0.5f * v * (1.f + erff(v * 0.70710678118654752f));
            } else if (EPI == 3) {
                v += ldin(bias, n, fp32);
                v = clampf(v + bf2f(resid[(size_t)m * Nn + n]), -1e6f, 1e6f);
            }
            Cm[(size_t)m * Nn + n] = f2bf(v);
        }
}

__global__ void gemm_ctx_fb(const bf16* __restrict__ KP, const bf16* __restrict__ V,
                            float* __restrict__ CTX) {
    __shared__ float Ks[32][33];
    __shared__ float Vs[32][33];
    int c0 = blockIdx.x * 32, f0 = blockIdx.y * 32;
    int tx = threadIdx.x, ty = threadIdx.y;
    int tid = ty * 16 + tx, lr = tid >> 5, lc = tid & 31;
    float acc[2][2] = {{0.f, 0.f}, {0.f, 0.f}};
    for (int n0 = 0; n0 < NTOKB; n0 += 32) {
#pragma unroll
        for (int i = 0; i < 4; i++) {
            int r = lr + 8 * i;
            Ks[r][lc] = bf2f(KP[(size_t)(n0 + r) * FF + f0 + lc]);
            Vs[r][lc] = bf2f(V[(size_t)(n0 + r) * CC + c0 + lc]);
        }
        __syncthreads();
#pragma unroll
        for (int kk = 0; kk < 32; kk++) {
            float a0 = Ks[kk][ty], a1 = Ks[kk][ty + 16];
            float b0 = Vs[kk][tx], b1 = Vs[kk][tx + 16];
            acc[0][0] += a0 * b0; acc[0][1] += a0 * b1;
            acc[1][0] += a1 * b0; acc[1][1] += a1 * b1;
        }
        __syncthreads();
    }
#pragma unroll
    for (int i = 0; i < 2; i++)
#pragma unroll
        for (int j = 0; j < 2; j++)
            CTX[(size_t)(f0 + ty + 16 * i) * CC + c0 + tx + 16 * j] =
                clampf(acc[i][j], -1e18f, 1e18f);
}

__global__ void gemm_attnout_fb(const bf16* __restrict__ QP, const float* __restrict__ CTX,
                                const float* __restrict__ DINV, bf16* __restrict__ T) {
    __shared__ float As[32][33];
    __shared__ float Bs[32][33];
    int c0 = blockIdx.x * 32, m0 = blockIdx.y * 32;
    int tx = threadIdx.x, ty = threadIdx.y;
    int tid = ty * 16 + tx, lr = tid >> 5, lc = tid & 31;
    float acc[2][2] = {{0.f, 0.f}, {0.f, 0.f}};
    for (int k0 = 0; k0 < FF; k0 += 32) {
#pragma unroll
        for (int i = 0; i < 4; i++) {
            int r = lr + 8 * i;
            As[r][lc] = bf2f(QP[(size_t)(m0 + r) * FF + k0 + lc]);
            Bs[r][lc] = CTX[(size_t)(k0 + r) * CC + c0 + lc];
        }
        __syncthreads();
#pragma unroll
        for (int kk = 0; kk < 32; kk++) {
            float a0 = As[ty][kk], a1 = As[ty + 16][kk];
            float b0 = Bs[kk][tx], b1 = Bs[kk][tx + 16];
            acc[0][0] += a0 * b0; acc[0][1] += a0 * b1;
            acc[1][0] += a1 * b0; acc[1][1] += a1 * b1;
        }
        __syncthreads();
    }
#pragma unroll
    for (int i = 0; i < 2; i++)
#pragma unroll
        for (int j = 0; j < 2; j++) {
            int t = m0 + ty + 16 * i;
            size_t idx = (size_t)t * CC + c0 + tx + 16 * j;
            float addv = clampf(acc[i][j] * DINV[t], -1e6f, 1e6f);
            T[idx] = f2bf(bf2f(T[idx]) + addv);
        }
}

__global__ void colsum_k(const bf16* __restrict__ KP, float* __restrict__ KPART) {
    int chunk = blockIdx.x;
    int f = threadIdx.x;
    const bf16* base = KP + (size_t)chunk * 128 * FF + f;
    float acc = 0.f;
    for (int i = 0; i < 128; i++) acc += bf2f(base[(size_t)i * FF]);
    KPART[(size_t)chunk * FF + f] = acc;
}

__global__ void ksum_reduce(const float* __restrict__ KPART, float* __restrict__ KSUM) {
    int f = threadIdx.x;
    float acc = 0.f;
#pragma unroll
    for (int c = 0; c < 32; c++) acc += KPART[(size_t)c * FF + f];
    KSUM[f] = acc;
}

__global__ void dinv_k(const bf16* __restrict__ QP, const float* __restrict__ KSUM,
                       float* __restrict__ DINV) {
    int t = blockIdx.x * 4 + (threadIdx.x >> 6);
    int lane = threadIdx.x & 63;
    const bf16* row = QP + (size_t)t * FF;
    float s = 0.f;
#pragma unroll
    for (int j = 0; j < 4; j++) { int c = lane + 64 * j; s += bf2f(row[c]) * KSUM[c]; }
    s = wave_sum(s);
    if (lane == 0) DINV[t] = fminf(1.f / fmaxf(s, 1e-30f), 1e6f);
}

// ============================================================================
//   FAST PATH: MFMA bf16 GEMM — BMxBN tile, 4 waves in 2x2, global_load_lds,
//   2-phase double-buffered K-loop (BK=32: R11 measured BK=64 regresses —
//   128B LDS pitch = 16-way bank conflict on fragment reads + occupancy drop).
//   Pointer-bump staging. EPI 6 = fused QKV, EPI 7 = fused proj (+row-scale),
//   EPI 8 = MLP2 + residual + transposed d_out store.
// ============================================================================
template <int BM, int BN, int EPI, bool TRANSC>
__global__ __launch_bounds__(256) void mgemm(
    const bf16* __restrict__ A, int lda, long long aZ,
    const void* __restrict__ Bv, int ldb, long long bZ,
    const void* __restrict__ bias, const float* __restrict__ diag,
    const float* __restrict__ dinv,
    bf16* __restrict__ Cb, int ldc,
    bf16* __restrict__ Cb2, bf16* __restrict__ Cb3, float* __restrict__ Cf,
    int MperZ, int Kc, int nchunk, const int* __restrict__ mode)
{
    constexpr int MI = BM / 32;          // per-wave 16-row tiles (wave covers BM/2)
    constexpr int NI = BN / 32;          // per-wave 16-col tiles (wave covers BN/2)
    __shared__ short As[2][BM][32];
    __shared__ short Bs[2][BN][32];
    int fp32 = *mode;
    int z = blockIdx.z;
    int bl = z / nchunk;
    int chunk = z - bl * nchunk;
    const short* Ag = (const short*)A + (size_t)bl * aZ;
    const short* Bg = (const short*)Bv + (size_t)bl * bZ;

    // XCD swizzle: n-blocks of one m-panel get linear ids differing by 8 so
    // round-robin dispatch puts them on the SAME XCD (A-panel L2 reuse).
    int bx = blockIdx.x, by = blockIdx.y;
    if ((gridDim.y & 7) == 0) {
        int NB = gridDim.x;
        int flat = by * NB + bx;
        int grp = flat / (8 * NB);
        int rem = flat - grp * 8 * NB;
        by = grp * 8 + (rem & 7);
        bx = rem >> 3;
    }
    int n0 = bx * BN, m0 = by * BM;

    int tid = threadIdx.x;
    int lane = tid & 63, wave = tid >> 6;
    int wm = wave >> 1, wn = wave & 1;
    int row16 = lane & 15, quad = lane >> 4;
    int lrow = lane >> 2, lcol = (lane & 3) * 8;

    f32x4 acc[MI][NI];
#pragma unroll
    for (int i = 0; i < MI; i++)
#pragma unroll
        for (int j = 0; j < NI; j++) acc[i][j] = {0.f, 0.f, 0.f, 0.f};

    const int arb = wave * (BM / 4);
    const int brb = wave * (BN / 4);

    int kBase = chunk * Kc;
    int nt = Kc >> 5;

    // per-thread global source pointers, computed ONCE, bumped +32 per K-step
    const short* aptr[BM / 64];
    const short* bptr[BN / 64];
#pragma unroll
    for (int t = 0; t < BM / 64; t++)
        aptr[t] = &Ag[(size_t)(m0 + arb + t * 16 + lrow) * lda + kBase + lcol];
#pragma unroll
    for (int t = 0; t < BN / 64; t++)
        bptr[t] = &Bg[(size_t)(n0 + brb + t * 16 + lrow) * ldb + kBase + lcol];

    auto stage = [&](int b) {
#pragma unroll
        for (int t = 0; t < BM / 64; t++) {
#if HAS_GLL
            gll16(aptr[t], &As[b][arb + t * 16][0]);
#else
            *(short8*)&As[b][arb + t * 16 + lrow][lcol] = *(const short8*)aptr[t];
#endif
            aptr[t] += 32;
        }
#pragma unroll
        for (int t = 0; t < BN / 64; t++) {
#if HAS_GLL
            gll16(bptr[t], &Bs[b][brb + t * 16][0]);
#else
            *(short8*)&Bs[b][brb + t * 16 + lrow][lcol] = *(const short8*)bptr[t];
#endif
            bptr[t] += 32;
        }
    };

    auto compute = [&](int b) {
        short8 af[MI], bfr[NI];
#pragma unroll
        for (int i = 0; i < MI; i++)
            af[i] = *(const short8*)&As[b][wm * (BM / 2) + i * 16 + row16][quad * 8];
#pragma unroll
        for (int j = 0; j < NI; j++)
            bfr[j] = *(const short8*)&Bs[b][wn * (BN / 2) + j * 16 + row16][quad * 8];
#pragma unroll
        for (int i = 0; i < MI; i++)
#pragma unroll
            for (int j = 0; j < NI; j++)
                acc[i][j] = __builtin_amdgcn_mfma_f32_16x16x32_bf16(af[i], bfr[j], acc[i][j], 0, 0, 0);
    };

    // prologue: fill buffer 0 (__syncthreads drains vmcnt so LDS is ready)
    stage(0);
    __syncthreads();

    int cur = 0;
    for (int t = 0; t + 1 < nt; ++t) {
        stage(cur ^ 1);                        // next tile in flight under MFMAs
        compute(cur);
        __syncthreads();                       // drains vmcnt(0): next buf complete
        cur ^= 1;
    }
    compute(cur);                              // last tile, no prefetch

    // ---- epilogue ----
    float bv[NI];
    if (EPI == 0 || EPI == 2 || EPI == 3 || EPI == 8) {
#pragma unroll
        for (int j = 0; j < NI; j++)
            bv[j] = ldin(bias, n0 + wn * (BN / 2) + j * 16 + row16, fp32);
    } else if (EPI == 6) {
#pragma unroll
        for (int j = 0; j < NI; j++)
            bv[j] = diag[n0 + wn * (BN / 2) + j * 16 + row16];   // packed fp32 QKV bias
    } else {
#pragma unroll
        for (int j = 0; j < NI; j++) bv[j] = 0.f;
    }

#pragma unroll
    for (int i = 0; i < MI; i++) {
        int mb = m0 + wm * (BM / 2) + i * 16 + quad * 4;
        float dg[4] = {0.f, 0.f, 0.f, 0.f};
        if (EPI == 1) {
#pragma unroll
            for (int r = 0; r < 4; r++) dg[r] = diag[mb + r];
        }
        if (EPI == 7) {
#pragma unroll
            for (int r = 0; r < 4; r++) dg[r] = diag[(size_t)bl * MperZ + mb + r];
        }
        float dvv[4] = {0.f, 0.f, 0.f, 0.f};
        if (EPI == 5 || EPI == 7) {
#pragma unroll
            for (int r = 0; r < 4; r++) dvv[r] = dinv[(size_t)bl * MperZ + mb + r];
        }
#pragma unroll
        for (int j = 0; j < NI; j++) {
            int n = n0 + wn * (BN / 2) + j * 16 + row16;
            if (EPI == 6) {
                // fused QKV: seg is block-uniform (BN=128 divides 256-wide segments)
                int seg = n0 >> 8;          // 0=Q, 1=K, 2=V
                int c = n & 255;
                if (seg == 2) {
                    ushort4v pack;
#pragma unroll
                    for (int r = 0; r < 4; r++)
                        pack[r] = f2bits(clampf(acc[i][j][r] + bv[j], -1e6f, 1e6f));
                    int blq = mb >> 12, tb = mb & 4095;
                    *(ushort4v*)((unsigned short*)Cb3 +
                        (size_t)blq * CC * NTOKB + (size_t)c * NTOKB + tb) = pack;
                } else {
                    bf16* dst = seg ? Cb2 : Cb;
#pragma unroll
                    for (int r = 0; r < 4; r++) {
                        float v = clampf(acc[i][j][r] + bv[j], -1e6f, 1e6f);
                        dst[(size_t)(mb + r) * CC + c] = f2bf(v);
                    }
                }
            } else if (EPI == 7) {
                // fused proj with row-scale: dot*scale applied in fp32 (Q/K not
                // renormalized in memory). z=0 -> QP row-major; z=1 -> KP^T.
                if (bl == 1) {
                    ushort4v pack;
#pragma unroll
                    for (int r = 0; r < 4; r++) {
                        float v = fminf(0.0625f * (__expf(fminf(acc[i][j][r] * dvv[r] - dg[r], 60.f)) + 1e-4f), 1e8f);
                        pack[r] = f2bits(v);
                    }
                    int blq = mb >> 12, tb = mb & 4095;
                    *(ushort4v*)((unsigned short*)Cb2 +
                        (size_t)blq * CC * NTOKB + (size_t)n * NTOKB + tb) = pack;
                } else {
#pragma unroll
                    for (int r = 0; r < 4; r++) {
                        float v = fminf(0.0625f * (__expf(fminf(acc[i][j][r] * dvv[r] - dg[r], 60.f)) + 1e-4f), 1e8f);
                        Cb[(size_t)(mb + r) * ldc + n] = f2bf(v);
                    }
                }
            } else if (EPI == 8) {
                // MLP2: bias + residual(Cb=T) -> bf16-round -> transposed d_out
                int blq = mb >> 12, tb = mb & 4095;
                if (fp32) {
                    f32x4 o;
#pragma unroll
                    for (int r = 0; r < 4; r++) {
                        float v = acc[i][j][r] + bv[j];
                        v = clampf(v + bf2f(Cb[(size_t)(mb + r) * ldc + n]), -1e6f, 1e6f);
                        o[r] = bf2f(f2bf(v));
                    }
                    *(f32x4*)((float*)Cb3 + ((size_t)blq * CC + n) * NTOKB + tb) = o;
                } else {
                    ushort4v pack;
#pragma unroll
                    for (int r = 0; r < 4; r++) {
                        float v = acc[i][j][r] + bv[j];
                        v = clampf(v + bf2f(Cb[(size_t)(mb + r) * ldc + n]), -1e6f, 1e6f);
                        pack[r] = f2bits(v);
                    }
                    *(ushort4v*)((unsigned short*)Cb3 + ((size_t)blq * CC + n) * NTOKB + tb) = pack;
                }
            } else if (TRANSC) {
                ushort4v pack;
#pragma unroll
                for (int r = 0; r < 4; r++) {
                    float v = acc[i][j][r];
                    if (EPI == 0) {
                        v = clampf(v + bv[j], -1e6f, 1e6f);
                    } else {   // EPI == 1
                        v = fminf(0.0625f * (__expf(fminf(v - dg[r], 60.f)) + 1e-4f), 1e8f);
                    }
                    pack[r] = f2bits(v);
                }
                int blq = mb >> 12, tb = mb & 4095;
                *(ushort4v*)((unsigned short*)Cb +
                    (size_t)blq * CC * NTOKB + (size_t)n * NTOKB + tb) = pack;
            } else {
#pragma unroll
                for (int r = 0; r < 4; r++) {
                    int m = mb + r;
                    float v = acc[i][j][r];
                    if (EPI == 0) {
                        v = clampf(v + bv[j], -1e6f, 1e6f);
                        Cb[(size_t)m * ldc + n] = f2bf(v);
                    } else if (EPI == 1) {
                        v = fminf(0.0625f * (__expf(fminf(v - dg[r], 60.f)) + 1e-4f), 1e8f);
                        Cb[(size_t)m * ldc + n] = f2bf(v);
                    } else if (EPI == 2) {
                        v += bv[j];
                        v = 0.5f * v * (1.f + fast_erf(v * 0.70710678118654752f));
                        Cb[(size_t)m * ldc + n] = f2bf(v);
                    } else if (EPI == 3) {
                        v += bv[j];
                        size_t idx = (size_t)m * ldc + n;
                        v = clampf(v + bf2f(Cb[idx]), -1e6f, 1e6f);
                        Cb[idx] = f2bf(v);
                    } else if (EPI == 4) {
                        Cf[(size_t)z * MperZ + (size_t)m * ldc + n] = v;
                    } else if (EPI == 5) {
                        size_t mg = (size_t)bl * MperZ + m;
                        float addv = clampf(v * dvv[r], -1e6f, 1e6f);
                        size_t idx = mg * ldc + n;
                        Cb[idx] = f2bf(bf2f(Cb[idx]) + addv);
                    }
                }
            }
        }
    }
}

// PART[z=bl*16+ch][f][c] (fp32) -> CTX_T[bl][c][f] (bf16)
__global__ void reduce_ctx(const float* __restrict__ PART, bf16* __restrict__ CTXT) {
    int f = blockIdx.x;
    int bl = blockIdx.y;
    int c = threadIdx.x;
    float s = 0.f;
#pragma unroll
    for (int ch = 0; ch < 16; ch++)
        s += PART[(((size_t)bl * 16 + ch) * FF + f) * CC + c];
    s = clampf(s, -1e18f, 1e18f);
    CTXT[((size_t)bl * CC + c) * FF + f] = f2bf(s);
}

__global__ void colsum_t(const bf16* __restrict__ KPT, float* __restrict__ KSUM) {
    int bl = blockIdx.y;
    int f = blockIdx.x * 4 + (threadIdx.x >> 6);
    int lane = threadIdx.x & 63;
    const short* row = (const short*)KPT + ((size_t)bl * FF + f) * NTOKB;
    float s = 0.f;
    for (int i = lane * 8; i < NTOKB; i += 512) {
        short8 v = *(const short8*)&row[i];
#pragma unroll
        for (int j = 0; j < 8; j++) s += s2f(v[j]);
    }
    s = wave_sum(s);
    if (lane == 0) KSUM[(size_t)bl * FF + f] = s;
}

__global__ void dinv_v(const bf16* __restrict__ QP, const float* __restrict__ KSUM,
                       float* __restrict__ DINV) {
    int bl = blockIdx.y;
    int t = blockIdx.x * 4 + (threadIdx.x >> 6);
    int lane = threadIdx.x & 63;
    const short* row = (const short*)QP + ((size_t)bl * NTOKB + t) * FF;
    const float* ks = KSUM + (size_t)bl * FF;
    short4v u = *(const short4v*)&row[lane * 4];
    float s = 0.f;
#pragma unroll
    for (int j = 0; j < 4; j++) s += s2f(u[j]) * ks[lane * 4 + j];
    s = wave_sum(s);
    if (lane == 0) DINV[(size_t)bl * NTOKB + t] = fminf(1.f / fmaxf(s, 1e-30f), 1e6f);
}

// ============================================================================
extern "C" void kernel_launch(void* const* d_in, const int* in_sizes, int n_in,
                              void* d_out, int out_size, void* d_ws, size_t ws_size,
                              hipStream_t stream) {
    const void* x    = d_in[0];
    const void* proj = d_in[1];
    const void* wq   = d_in[2];
    const void* bq   = d_in[3];
    const void* wk   = d_in[4];
    const void* bk   = d_in[5];
    const void* wa   = d_in[6];
    const void* ba   = d_in[7];
    const void* g1   = d_in[8];
    const void* b1   = d_in[9];
    const void* g2   = d_in[10];
    const void* b2   = d_in[11];
    const void* w1   = d_in[12];
    const void* fb1  = d_in[13];
    const void* w2   = d_in[14];
    const void* fb2  = d_in[15];

    char* base = (char*)d_ws;
    const size_t MB = 1048576ull;
    const bool fast = ws_size >= 168 * MB;   // ws confirmed 256 MiB

    if (fast) {
        // ---- full-batch layout (peak ~167 MiB) ----
        bf16* T    = (bf16*)base;                    // [0,16M)
        bf16* Hs   = (bf16*)(base + 16 * MB);        // [16,32M)  H -> QP -> H2
        bf16* Qs   = (bf16*)(base + 32 * MB);        // [32,48M)  Q
        bf16* Ks   = (bf16*)(base + 48 * MB);        // [48,64M)  K  (contiguous after Qs)
        bf16* VT   = (bf16*)(base + 64 * MB);        // [64,80M)  V_T
        bf16* KPT  = (bf16*)(base + 80 * MB);        // [80,96M)  KP_T
        bf16* MID  = (bf16*)(base + 96 * MB);        // [96,160M) MLP hidden
        float* PART = (float*)(base + 96 * MB);      // 34M fp32; dead before MID written
        char* sm = base + 160 * MB;
        int* MODE = (int*)sm;
        float* DIAGQ = (float*)(sm + 1024);          // NTOK  (DIAGK contiguous after)
        float* DIAGK = DIAGQ + NTOK;
        float* DINV  = DIAGK + NTOK;
        float* KSUM  = DINV + NTOK;                  // BB*FF
        float* SCALEQ = KSUM + BB * FF;              // NTOK  (SCALEK contiguous after)
        float* SCALEK = SCALEQ + NTOK;
        bf16* CTXT   = (bf16*)(sm + 2 * MB);         // 1M
        bf16* WB     = (bf16*)(sm + 4 * MB);         // 1.5M
        float* BQKV  = (float*)(sm + 6 * MB);        // 3KB

        detect_mode<<<1, 64, 0, stream>>>(x, MODE);
        convw_all<<<3075, 256, 0, stream>>>(wq, wk, wa, proj, w1, w2,
                                            bq, bk, ba, WB, BQKV, MODE);
        // fused transpose + LN1: writes T (residual) and Hs (LN out)
        trans_ln<<<dim3(NTOKB / 32, BB), 256, 0, stream>>>(x, g1, b1, T, Hs, MODE);

        // fused QKV: M=32768 N=768 K=256; grid (6, 256) = 1536 blocks
        mgemm<128, 128, 6, false><<<dim3(6, 256, 1), 256, 0, stream>>>(
            Hs, 256, 0, WB, 256, 0, nullptr, BQKV, nullptr,
            Qs, 256, Ks, VT, nullptr, 0, 256, 1, MODE);
        // read-only row scale for Q and K in ONE launch (y=0:Q, y=1:K)
        rowscale2<<<dim3(NTOK / 4, 2), 256, 0, stream>>>(Qs, SCALEQ, DIAGQ);
        // fused proj: z=0 Q->QP(Hs), z=1 K->KP^T(KPT); scale applied in epilogue
        mgemm<128, 128, 7, false><<<dim3(2, 256, 2), 256, 0, stream>>>(
            Qs, 256, 8388608LL /*Ks-Qs elems*/, WB + 196608, 256, 0,
            nullptr, DIAGQ, SCALEQ,
            Hs, 256, KPT, nullptr, nullptr, NTOK, 256, 1, MODE);
        bf16* QP = Hs;
        colsum_t<<<dim3(FF / 4, BB), 256, 0, stream>>>(KPT, KSUM);
        dinv_v<<<dim3(NTOKB / 4, BB), 256, 0, stream>>>(QP, KSUM, DINV);
        // ctx: M=F=256, N=C=256, K=4096 split 16; z = 8 batches * 16 chunks = 128
        mgemm<64, 128, 4, false><<<dim3(2, 4, BB * 16), 256, 0, stream>>>(
            KPT, NTOKB, (long long)FF * NTOKB, VT, NTOKB, (long long)CC * NTOKB,
            nullptr, nullptr, nullptr,
            nullptr, CC, nullptr, nullptr, PART, FF * CC, 256, 16, MODE);
        reduce_ctx<<<dim3(FF, BB), 256, 0, stream>>>(PART, CTXT);
        // attnout: M=4096/batch, N=256, K=256; BN=64 -> (4, 32, 8) = 1024 blocks
        mgemm<128, 64, 5, false><<<dim3(4, 32, BB), 256, 0, stream>>>(
            QP, 256, (long long)NTOKB * FF, CTXT, FF, (long long)CC * FF,
            nullptr, nullptr, DINV,
            T, 256, nullptr, nullptr, nullptr, NTOKB, 256, 1, MODE);
        // MLP
        layernorm_v<<<NTOK / 4, 256, 0, stream>>>(T, g2, b2, Hs, MODE);
        mgemm<128, 128, 2, false><<<dim3(8, 256, 1), 256, 0, stream>>>(
            Hs, 256, 0, WB + 262144, 256, 0, fb1, nullptr, nullptr,
            MID, 1024, nullptr, nullptr, nullptr, 0, 256, 1, MODE);
        // MLP2 fused with residual + transposed output store (EPI 8)
        mgemm<128, 128, 8, false><<<dim3(2, 256, 1), 256, 0, stream>>>(
            MID, 1024, 0, WB + 524288, 1024, 0, fb2, nullptr, nullptr,
            T, 256, nullptr, (bf16*)d_out, nullptr, 0, 1024, 1, MODE);
        return;
    }

    // ================= FALLBACK: proven R5 per-batch path =================
    bf16* Tb   = (bf16*)(base);
    bf16* Hb   = (bf16*)(base + 2 * MB);
    bf16* Qb   = (bf16*)(base + 4 * MB);
    bf16* Kb   = (bf16*)(base + 6 * MB);
    bf16* Vb   = (bf16*)(base + 8 * MB);
    bf16* QPb  = (bf16*)(base + 2 * MB);
    bf16* KPb  = (bf16*)(base + 4 * MB);
    bf16* MIDb = (bf16*)(base + 2 * MB);
    bf16* H2b  = (bf16*)(base + 10 * MB);
    char* sm   = base + 12 * MB;
    int*   MODE  = (int*)sm;
    float* DIAGQ = (float*)(sm + 256);
    float* DIAGK = DIAGQ + NTOKB;
    float* DINV  = DIAGK + NTOKB;
    float* KSUM  = DINV + NTOKB;
    float* KPART = KSUM + FF;
    float* CTX   = KPART + 32 * FF;

    dim3 tb32(32, 8);
    dim3 tb16(16, 16);
    dim3 gq(CC / 32, NTOKB / 32);

    detect_mode<<<1, 64, 0, stream>>>(x, MODE);

    for (int b = 0; b < BB; b++) {
        size_t eoff = (size_t)b * CC * NTOKB;
        transpose_in_off<<<dim3(NTOKB / 32, CC / 32), tb32, 0, stream>>>(x, Tb, MODE, eoff);
        layernorm_k<<<NTOKB / 4, 256, 0, stream>>>(Tb, g1, b1, Hb, MODE);
        gemm_nt<0><<<gq, tb16, 0, stream>>>(Hb, wq, bq, nullptr, nullptr, Qb, NTOKB, CC, CC, MODE);
        gemm_nt<0><<<gq, tb16, 0, stream>>>(Hb, wk, bk, nullptr, nullptr, Kb, NTOKB, CC, CC, MODE);
        gemm_nt<0><<<gq, tb16, 0, stream>>>(Hb, wa, ba, nullptr, nullptr, Vb, NTOKB, CC, CC, MODE);
        rownorm_k<<<NTOKB / 4, 256, 0, stream>>>(Qb, DIAGQ);
        rownorm_k<<<NTOKB / 4, 256, 0, stream>>>(Kb, DIAGK);
        gemm_nt<1><<<gq, tb16, 0, stream>>>(Qb, proj, nullptr, DIAGQ, nullptr, QPb, NTOKB, FF, CC, MODE);
        gemm_nt<1><<<gq, tb16, 0, stream>>>(Kb, proj, nullptr, DIAGK, nullptr, KPb, NTOKB, FF, CC, MODE);
        colsum_k<<<32, 256, 0, stream>>>(KPb, KPART);
        ksum_reduce<<<1, 256, 0, stream>>>(KPART, KSUM);
        dinv_k<<<NTOKB / 4, 256, 0, stream>>>(QPb, KSUM, DINV);
        gemm_ctx_fb<<<dim3(CC / 32, FF / 32), tb16, 0, stream>>>(KPb, Vb, CTX);
        gemm_attnout_fb<<<gq, tb16, 0, stream>>>(QPb, CTX, DINV, Tb);
        layernorm_k<<<NTOKB / 4, 256, 0, stream>>>(Tb, g2, b2, H2b, MODE);
        gemm_nt<2><<<dim3(HIDDEN / 32, NTOKB / 32), tb16, 0, stream>>>(H2b, w1, fb1, nullptr, nullptr, MIDb, NTOKB, HIDDEN, CC, MODE);
        gemm_nt<3><<<gq, tb16, 0, stream>>>(MIDb, w2, fb2, nullptr, Tb, Tb, NTOKB, CC, HIDDEN, MODE);
        transpose_out_off<<<dim3(CC / 32, NTOKB / 32), tb32, 0, stream>>>(Tb, d_out, MODE, eoff);
    }
}